// Round 1
// baseline (701.491 us; speedup 1.0000x reference)
//
#include <hip/hip_runtime.h>
#include <math.h>

#define HEADS 2
#define C1    33
#define C2    550
#define D1    66     // HEADS*C1
#define D2    1100   // HEADS*C2
#define IN1   256
#define NT    16     // node tile for final GEMM

// ---------------- CSR construction ----------------
__global__ void k_hist(const int* __restrict__ dst, int E, int* __restrict__ cnt) {
    int e = blockIdx.x * blockDim.x + threadIdx.x;
    if (e < E) atomicAdd(&cnt[dst[e]], 1);
}

__global__ void k_scan(const int* __restrict__ cnt, int* __restrict__ roff,
                       int* __restrict__ pos, int N) {
    __shared__ int sb[1024];
    __shared__ int carry_s;
    if (threadIdx.x == 0) { carry_s = 0; roff[0] = 0; }
    __syncthreads();
    for (int base = 0; base < N; base += 1024) {
        int i = base + (int)threadIdx.x;
        int v = (i < N) ? cnt[i] : 0;
        sb[threadIdx.x] = v;
        __syncthreads();
        for (int s = 1; s < 1024; s <<= 1) {
            int t = (threadIdx.x >= s) ? sb[threadIdx.x - s] : 0;
            __syncthreads();
            sb[threadIdx.x] += t;
            __syncthreads();
        }
        int carry = carry_s;
        if (i < N) {
            int incl = carry + sb[threadIdx.x];
            roff[i + 1] = incl;
            pos[i] = incl - v;
        }
        __syncthreads();
        if (threadIdx.x == 0) carry_s = carry + sb[1023];
        __syncthreads();
    }
}

__global__ void k_fill(const int* __restrict__ src, const int* __restrict__ dst, int E,
                       int* __restrict__ pos, int* __restrict__ elist) {
    int e = blockIdx.x * blockDim.x + threadIdx.x;
    if (e < E) {
        int slot = atomicAdd(&pos[dst[e]], 1);
        elist[slot] = src[e];
    }
}

// ---------------- conv1 projections: q1,k1,v1,s1 = x @ W + b ----------------
__global__ __launch_bounds__(256) void k_gemm1(
        const float* __restrict__ x,
        const float* __restrict__ Wq, const float* __restrict__ bq,
        const float* __restrict__ Wk, const float* __restrict__ bk,
        const float* __restrict__ Wv, const float* __restrict__ bv,
        const float* __restrict__ Ws, const float* __restrict__ bs,
        float* __restrict__ q1, float* __restrict__ k1,
        float* __restrict__ v1, float* __restrict__ s1, int N) {
    __shared__ float xs[IN1];
    int n = blockIdx.x;
    const float* xr = x + (size_t)n * IN1;
    if (threadIdx.x < IN1) xs[threadIdx.x] = xr[threadIdx.x];
    __syncthreads();
    for (int t = threadIdx.x; t < 4 * D1; t += blockDim.x) {
        int m = t / D1, j = t % D1;
        const float* W; const float* b; float* o;
        switch (m) {
            case 0: W = Wq; b = bq; o = q1; break;
            case 1: W = Wk; b = bk; o = k1; break;
            case 2: W = Wv; b = bv; o = v1; break;
            default: W = Ws; b = bs; o = s1; break;
        }
        float acc = 0.f;
        #pragma unroll 8
        for (int k = 0; k < IN1; k++) acc += xs[k] * W[k * D1 + j];
        o[(size_t)n * D1 + j] = acc + b[j];
    }
}

// ---------------- conv1 edge phase (flash-style online softmax) ----------------
__global__ __launch_bounds__(128) void k_conv1(
        const float* __restrict__ q1, const float* __restrict__ k1,
        const float* __restrict__ v1, const float* __restrict__ s1,
        const int* __restrict__ roff, const int* __restrict__ elist,
        float* __restrict__ h1, int N) {
    int n = blockIdx.x;
    int h = threadIdx.x >> 6;      // wave = head
    int lane = threadIdx.x & 63;
    int base = n * D1 + h * C1;
    float my_q = (lane < C1) ? q1[base + lane] : 0.f;
    float m = -INFINITY, lsum = 0.f, acc = 0.f;
    int e0 = roff[n], e1 = roff[n + 1];
    const float isc = 0.17407765595569785f;  // 1/sqrt(33)
    for (int e = e0; e < e1; e++) {
        int s = elist[e];
        int sb = s * D1 + h * C1;
        float kv = (lane < C1) ? k1[sb + lane] : 0.f;
        float prod = my_q * kv;
        #pragma unroll
        for (int off = 32; off >= 1; off >>= 1) prod += __shfl_xor(prod, off, 64);
        float alpha = prod * isc;
        float mnew = fmaxf(m, alpha);
        float scale = __expf(m - mnew);   // first iter: exp(-inf)=0
        float p = __expf(alpha - mnew);
        lsum = lsum * scale + p;
        float vv = (lane < C1) ? v1[sb + lane] : 0.f;
        acc = acc * scale + p * vv;
        m = mnew;
    }
    if (lane < C1) {
        float res = (lsum > 0.f) ? acc / lsum : 0.f;
        h1[n * D1 + h * C1 + lane] = res + s1[base + lane];
    }
}

// ---------------- precompute G = Wq2_h Wk2_h^T, bias foldings ----------------
__global__ __launch_bounds__(128) void k_precomp(
        const float* __restrict__ Wq2, const float* __restrict__ bq2,
        const float* __restrict__ Wk2, const float* __restrict__ bk2,
        float* __restrict__ G, float* __restrict__ wqbk,
        float* __restrict__ wkbq, float* __restrict__ cc) {
    int h = blockIdx.x / D1;
    int a = blockIdx.x % D1;
    const float* wqa = Wq2 + (size_t)a * D2 + h * C2;
    for (int b = threadIdx.x; b < D1; b += blockDim.x) {
        const float* wkb = Wk2 + (size_t)b * D2 + h * C2;
        float acc = 0.f;
        for (int c = 0; c < C2; c++) acc += wqa[c] * wkb[c];
        G[h * D1 * D1 + a * D1 + b] = acc;
    }
    if (threadIdx.x == 66) {
        const float* bkh = bk2 + h * C2;
        float acc = 0.f;
        for (int c = 0; c < C2; c++) acc += wqa[c] * bkh[c];
        wqbk[h * D1 + a] = acc;
    }
    if (threadIdx.x == 67) {
        const float* wka = Wk2 + (size_t)a * D2 + h * C2;
        const float* bqh = bq2 + h * C2;
        float acc = 0.f;
        for (int c = 0; c < C2; c++) acc += wka[c] * bqh[c];
        wkbq[h * D1 + a] = acc;
    }
    if (blockIdx.x == 0 && threadIdx.x >= 68 && threadIdx.x < 70) {
        int hh = threadIdx.x - 68;
        const float* bqh = bq2 + hh * C2;
        const float* bkh = bk2 + hh * C2;
        float acc = 0.f;
        for (int c = 0; c < C2; c++) acc += bqh[c] * bkh[c];
        cc[hh] = acc;
    }
}

// ---------------- z = G·h1 per node, plus bias dot scalars ----------------
__global__ __launch_bounds__(192) void k_z(
        const float* __restrict__ h1, const float* __restrict__ G,
        const float* __restrict__ wqbk, const float* __restrict__ wkbq,
        float* __restrict__ z, float* __restrict__ ad, float* __restrict__ as_, int N) {
    __shared__ float hs[D1];
    int n = blockIdx.x;
    if (threadIdx.x < D1) hs[threadIdx.x] = h1[(size_t)n * D1 + threadIdx.x];
    __syncthreads();
    int t = threadIdx.x;
    if (t < 2 * D1) {
        const float* Gr = G + t * D1;   // t = h*66+a  → row (h,a)
        float acc = 0.f;
        #pragma unroll 6
        for (int b = 0; b < D1; b++) acc += Gr[b] * hs[b];
        z[(size_t)n * 2 * D1 + t] = acc;
    } else if (t < 2 * D1 + 2) {
        int h = t - 2 * D1;
        const float* w = wqbk + h * D1;
        float acc = 0.f;
        for (int b = 0; b < D1; b++) acc += w[b] * hs[b];
        ad[n * 2 + h] = acc;
    } else if (t < 2 * D1 + 4) {
        int h = t - 2 * D1 - 2;
        const float* w = wkbq + h * D1;
        float acc = 0.f;
        for (int b = 0; b < D1; b++) acc += w[b] * hs[b];
        as_[n * 2 + h] = acc;
    }
}

// ---------------- conv2 edge phase: alpha via 66-dot, aggregate h1[src] ----------------
__global__ __launch_bounds__(128) void k_conv2(
        const float* __restrict__ h1, const float* __restrict__ z,
        const float* __restrict__ ad, const float* __restrict__ as_,
        const float* __restrict__ cc, const int* __restrict__ roff,
        const int* __restrict__ elist, float* __restrict__ agg,
        float* __restrict__ flag, int N) {
    int n = blockIdx.x;
    int h = threadIdx.x >> 6;
    int lane = threadIdx.x & 63;
    int c0 = lane, c1 = lane + 64;
    bool ok1 = (c1 < D1);
    float hd0 = h1[(size_t)n * D1 + c0];
    float hd1 = ok1 ? h1[(size_t)n * D1 + c1] : 0.f;
    float adv = ad[n * 2 + h] + cc[h];
    float m = -INFINITY, lsum = 0.f, a0 = 0.f, a1 = 0.f;
    int e0 = roff[n], e1 = roff[n + 1];
    const float isc = 0.04264014327112209f;  // 1/sqrt(550)
    for (int e = e0; e < e1; e++) {
        int s = elist[e];
        const float* zr = z + (size_t)s * 2 * D1 + h * D1;
        float prod = hd0 * zr[c0] + (ok1 ? hd1 * zr[c1] : 0.f);
        #pragma unroll
        for (int off = 32; off >= 1; off >>= 1) prod += __shfl_xor(prod, off, 64);
        float alpha = (prod + adv + as_[s * 2 + h]) * isc;
        float mnew = fmaxf(m, alpha);
        float scale = __expf(m - mnew);
        float p = __expf(alpha - mnew);
        lsum = lsum * scale + p;
        float v0 = h1[(size_t)s * D1 + c0];
        float vv1 = ok1 ? h1[(size_t)s * D1 + c1] : 0.f;
        a0 = a0 * scale + p * v0;
        a1 = a1 * scale + p * vv1;
        m = mnew;
    }
    float inv = (lsum > 0.f) ? 1.f / lsum : 0.f;
    agg[(size_t)n * 2 * D1 + h * D1 + c0] = a0 * inv;
    if (ok1) agg[(size_t)n * 2 * D1 + h * D1 + c1] = a1 * inv;
    if (lane == 0) flag[n * 2 + h] = (lsum > 0.f) ? 1.f : 0.f;
}

// ---------------- final: h2 = agg@Wv2 + flag*bv2 + h1@Ws2 + bs2; pair-max ----------------
__global__ __launch_bounds__(256) void k_final(
        const float* __restrict__ agg, const float* __restrict__ h1,
        const float* __restrict__ flag,
        const float* __restrict__ Wv2, const float* __restrict__ bv2,
        const float* __restrict__ Ws2, const float* __restrict__ bs2,
        float* __restrict__ out, int N) {
    __shared__ float aggs[NT][2 * D1];
    __shared__ float h1s[NT][D1];
    __shared__ float fl[NT][2];
    int n0 = blockIdx.x * NT;
    int t = threadIdx.x;
    for (int i = t; i < NT * 2 * D1; i += 256) {
        int nn = i / (2 * D1), c = i % (2 * D1);
        aggs[nn][c] = (n0 + nn < N) ? agg[(size_t)(n0 + nn) * 2 * D1 + c] : 0.f;
    }
    for (int i = t; i < NT * D1; i += 256) {
        int nn = i / D1, c = i % D1;
        h1s[nn][c] = (n0 + nn < N) ? h1[(size_t)(n0 + nn) * D1 + c] : 0.f;
    }
    if (t < NT * 2) {
        int nn = t / 2;
        fl[nn][t % 2] = (n0 + nn < N) ? flag[(n0 + nn) * 2 + (t % 2)] : 0.f;
    }
    __syncthreads();

    float acc[NT][5];
    #pragma unroll
    for (int n = 0; n < NT; n++)
        #pragma unroll
        for (int r = 0; r < 5; r++) acc[n][r] = 0.f;

    // columns: j = t + 256*r. r=0,1 → head0; r=3,4 → head1; r=2 mixed.
    int j2 = t + 512;
    bool h2sel = (j2 >= C2);
    bool jok4 = (t + 1024) < D2;

    for (int b = 0; b < D1; b++) {
        float wv0 = Wv2[b * D2 + t];
        float wv1 = Wv2[b * D2 + t + 256];
        float wv2 = Wv2[b * D2 + t + 512];
        float wv3 = Wv2[b * D2 + t + 768];
        float wv4 = jok4 ? Wv2[b * D2 + t + 1024] : 0.f;
        float ws0 = Ws2[b * D2 + t];
        float ws1 = Ws2[b * D2 + t + 256];
        float ws2v = Ws2[b * D2 + t + 512];
        float ws3 = Ws2[b * D2 + t + 768];
        float ws4 = jok4 ? Ws2[b * D2 + t + 1024] : 0.f;
        #pragma unroll
        for (int n = 0; n < NT; n++) {
            float hv = h1s[n][b];
            float a0 = aggs[n][b];
            float a1 = aggs[n][D1 + b];
            float sel = h2sel ? a1 : a0;
            acc[n][0] += a0 * wv0 + hv * ws0;
            acc[n][1] += a0 * wv1 + hv * ws1;
            acc[n][2] += sel * wv2 + hv * ws2v;
            acc[n][3] += a1 * wv3 + hv * ws3;
            acc[n][4] += a1 * wv4 + hv * ws4;
        }
    }

    float bvv[5], bss[5];
    int hh[5];
    #pragma unroll
    for (int r = 0; r < 5; r++) {
        int j = t + 256 * r;
        bool ok = j < D2;
        bvv[r] = ok ? bv2[j] : 0.f;
        bss[r] = ok ? bs2[j] : 0.f;
        hh[r] = (j >= C2) ? 1 : 0;
    }
    #pragma unroll
    for (int n = 0; n < NT; n++) {
        #pragma unroll
        for (int r = 0; r < 5; r++) {
            int j = t + 256 * r;
            float val = acc[n][r] + fl[n][hh[r]] * bvv[r] + bss[r];
            float part = __shfl_xor(val, 1, 64);
            if (j < D2 && ((j & 1) == 0) && (n0 + n < N)) {
                out[(size_t)(n0 + n) * C2 + (j >> 1)] = fmaxf(val, part);
            }
        }
    }
}

// ---------------- launcher ----------------
extern "C" void kernel_launch(void* const* d_in, const int* in_sizes, int n_in,
                              void* d_out, int out_size, void* d_ws, size_t ws_size,
                              hipStream_t stream) {
    const float* x  = (const float*)d_in[0];
    const int*   ei = (const int*)d_in[1];
    int N = in_sizes[0] / IN1;
    int E = in_sizes[1] / 2;
    const int* src = ei;
    const int* dst = ei + E;

    const float *Wq1 = (const float*)d_in[2],  *bq1 = (const float*)d_in[3];
    const float *Wk1 = (const float*)d_in[4],  *bk1 = (const float*)d_in[5];
    const float *Wv1 = (const float*)d_in[6],  *bv1 = (const float*)d_in[7];
    const float *Ws1 = (const float*)d_in[8],  *bs1 = (const float*)d_in[9];
    const float *Wq2 = (const float*)d_in[10], *bq2 = (const float*)d_in[11];
    const float *Wk2 = (const float*)d_in[12], *bk2 = (const float*)d_in[13];
    const float *Wv2 = (const float*)d_in[14], *bv2 = (const float*)d_in[15];
    const float *Ws2 = (const float*)d_in[16], *bs2 = (const float*)d_in[17];

    // workspace layout (with aliasing: z over q1+k1, agg over v1+s1)
    float* f  = (float*)d_ws;
    float* q1 = f;
    float* k1 = q1 + (size_t)N * D1;
    float* v1 = k1 + (size_t)N * D1;
    float* s1 = v1 + (size_t)N * D1;
    float* h1 = s1 + (size_t)N * D1;
    float* z   = q1;   // N*132, valid after conv1 done
    float* agg = v1;   // N*132, valid after conv1 done
    float* ad   = h1 + (size_t)N * D1;   // N*2
    float* as_  = ad + (size_t)N * 2;    // N*2
    float* flag = as_ + (size_t)N * 2;   // N*2
    float* G    = flag + (size_t)N * 2;  // 2*66*66
    float* wqbk = G + 2 * D1 * D1;       // 132
    float* wkbq = wqbk + 2 * D1;         // 132
    float* cc   = wkbq + 2 * D1;         // 2
    int* cnt   = (int*)(cc + 2);
    int* roff  = cnt + N;
    int* pos   = roff + N + 1;
    int* elist = pos + N;

    // CSR by dst
    hipMemsetAsync(cnt, 0, (size_t)N * sizeof(int), stream);
    k_hist<<<(E + 255) / 256, 256, 0, stream>>>(dst, E, cnt);
    k_scan<<<1, 1024, 0, stream>>>(cnt, roff, pos, N);
    k_fill<<<(E + 255) / 256, 256, 0, stream>>>(src, dst, E, pos, elist);

    // conv1
    k_gemm1<<<N, 256, 0, stream>>>(x, Wq1, bq1, Wk1, bk1, Wv1, bv1, Ws1, bs1,
                                   q1, k1, v1, s1, N);
    k_conv1<<<N, 128, 0, stream>>>(q1, k1, v1, s1, roff, elist, h1, N);

    // conv2 precompute + z
    k_precomp<<<2 * D1, 128, 0, stream>>>(Wq2, bq2, Wk2, bk2, G, wqbk, wkbq, cc);
    k_z<<<N, 192, 0, stream>>>(h1, G, wqbk, wkbq, z, ad, as_, N);

    // conv2 edge phase
    k_conv2<<<N, 128, 0, stream>>>(h1, z, ad, as_, cc, roff, elist, agg, flag, N);

    // final fused GEMM + bias + skip + pair-max
    k_final<<<(N + NT - 1) / NT, 256, 0, stream>>>(agg, h1, flag, Wv2, bv2, Ws2, bs2,
                                                   (float*)d_out, N);
}

// Round 2
// 326.181 us; speedup vs baseline: 2.1506x; 2.1506x over previous
//
#include <hip/hip_runtime.h>
#include <math.h>

#define HEADS 2
#define C1    33
#define C2    550
#define D1    66     // HEADS*C1
#define D2    1100   // HEADS*C2
#define IN1   256
#define PROJW 288    // padded q|k|v|s width (264 -> 288 = 3*96)
#define KU    224    // padded U width (198 -> 224 = 7*32)
#define N2P   1152   // padded final cols (1100 -> 1152 = 12*96)

typedef __attribute__((ext_vector_type(8))) short bfrag;   // 8 bf16 (bits in short)
typedef __attribute__((ext_vector_type(4))) float f32x4;

__device__ inline unsigned short f2bf(float f) {
    unsigned int u = __float_as_uint(f);
    u += 0x7FFFu + ((u >> 16) & 1u);
    return (unsigned short)(u >> 16);
}

// ---------------- fp32 -> bf16 conversion of x ----------------
__global__ void k_cvt(const float* __restrict__ x, unsigned short* __restrict__ xb, int total4) {
    int i = blockIdx.x * blockDim.x + threadIdx.x;
    if (i >= total4) return;
    float4 v = ((const float4*)x)[i];
    ushort4 o;
    o.x = f2bf(v.x); o.y = f2bf(v.y); o.z = f2bf(v.z); o.w = f2bf(v.w);
    ((ushort4*)xb)[i] = o;
}

// ---------------- build Wt1 [288][256] bf16 + bcat[288] ----------------
__global__ void k_prep1(const float* __restrict__ Wq, const float* __restrict__ bq,
                        const float* __restrict__ Wk, const float* __restrict__ bk,
                        const float* __restrict__ Wv, const float* __restrict__ bv,
                        const float* __restrict__ Ws, const float* __restrict__ bs,
                        unsigned short* __restrict__ Wt1, float* __restrict__ bcat) {
    int c = blockIdx.x;          // output col 0..287
    int k = threadIdx.x;         // 0..255
    float val = 0.f, bia = 0.f;
    if (c < 4 * D1) {
        int m = c / D1, j = c % D1;
        const float* W; const float* B;
        switch (m) {
            case 0: W = Wq; B = bq; break;
            case 1: W = Wk; B = bk; break;
            case 2: W = Wv; B = bv; break;
            default: W = Ws; B = bs; break;
        }
        val = W[(size_t)k * D1 + j];
        bia = B[j];
    }
    Wt1[(size_t)c * IN1 + k] = f2bf(val);
    if (k == 0) bcat[c] = bia;
}

// ---------------- build W2t [1152][224] bf16 + padded biases ----------------
__global__ void k_prep2(const float* __restrict__ Wv2, const float* __restrict__ bv2,
                        const float* __restrict__ Ws2, const float* __restrict__ bs2,
                        unsigned short* __restrict__ W2t,
                        float* __restrict__ bvp, float* __restrict__ bsp) {
    int c = blockIdx.x;          // 0..1151
    int k = threadIdx.x;         // 0..255 (guard 224)
    if (k < KU) {
        float val = 0.f;
        if (c < D2) {
            int h = (c >= C2) ? 1 : 0;
            if (!h) {
                if (k < 66) val = Wv2[(size_t)k * D2 + c];
                else if (k >= 132 && k < 198) val = Ws2[(size_t)(k - 132) * D2 + c];
            } else {
                if (k >= 66 && k < 132) val = Wv2[(size_t)(k - 66) * D2 + c];
                else if (k >= 132 && k < 198) val = Ws2[(size_t)(k - 132) * D2 + c];
            }
        }
        W2t[(size_t)c * KU + k] = f2bf(val);
    }
    if (k == 0) {
        bvp[c] = (c < D2) ? bv2[c] : 0.f;
        bsp[c] = (c < D2) ? bs2[c] : 0.f;
    }
}

// ---------------- CSR construction ----------------
__global__ void k_hist(const int* __restrict__ dst, int E, int* __restrict__ cnt) {
    int e = blockIdx.x * blockDim.x + threadIdx.x;
    if (e < E) atomicAdd(&cnt[dst[e]], 1);
}

__global__ void k_scan(const int* __restrict__ cnt, int* __restrict__ roff,
                       int* __restrict__ pos, int N) {
    __shared__ int wsum[16];
    __shared__ int carry_s;
    int tid = threadIdx.x, wid = tid >> 6, lane = tid & 63;
    if (tid == 0) { carry_s = 0; roff[0] = 0; }
    __syncthreads();
    for (int base = 0; base < N; base += 1024) {
        int i = base + tid;
        int v = (i < N) ? cnt[i] : 0;
        int x = v;
        #pragma unroll
        for (int s = 1; s < 64; s <<= 1) {
            int t = __shfl_up(x, s, 64);
            if (lane >= s) x += t;
        }
        if (lane == 63) wsum[wid] = x;
        __syncthreads();
        if (tid < 16) {
            int y = wsum[tid];
            #pragma unroll
            for (int s = 1; s < 16; s <<= 1) {
                int t = __shfl_up(y, s, 16);
                if (tid >= s) y += t;
            }
            wsum[tid] = y;
        }
        __syncthreads();
        int carry = carry_s;
        int incl = carry + (wid ? wsum[wid - 1] : 0) + x;
        if (i < N) { roff[i + 1] = incl; pos[i] = incl - v; }
        __syncthreads();
        if (tid == 0) carry_s = carry + wsum[15];
        __syncthreads();
    }
}

__global__ void k_fill(const int* __restrict__ src, const int* __restrict__ dst, int E,
                       int* __restrict__ pos, int* __restrict__ elist) {
    int e = blockIdx.x * blockDim.x + threadIdx.x;
    if (e < E) {
        int slot = atomicAdd(&pos[dst[e]], 1);
        elist[slot] = src[e];
    }
}

// ---------------- MFMA GEMM 1: proj[N][288] = x_bf16[N][256] @ Wt1^T + bcat ----------------
__global__ __launch_bounds__(256) void k_mm1(
        const unsigned short* __restrict__ A, const unsigned short* __restrict__ B,
        const float* __restrict__ bias, float* __restrict__ proj, int N) {
    int wave = threadIdx.x >> 6, lane = threadIdx.x & 63;
    int lr = lane & 15, lk = lane >> 4;
    int rbase = blockIdx.x * 128 + (wave >> 1) * 64;
    int cbase = blockIdx.y * 96 + (wave & 1) * 48;
    f32x4 acc[4][3];
    #pragma unroll
    for (int i = 0; i < 4; i++)
        #pragma unroll
        for (int j = 0; j < 3; j++) acc[i][j] = (f32x4){0.f, 0.f, 0.f, 0.f};
    int ar[4];
    #pragma unroll
    for (int mi = 0; mi < 4; mi++) {
        int r = rbase + mi * 16 + lr;
        ar[mi] = (r < N) ? r : (N - 1);
    }
    for (int k0 = 0; k0 < IN1; k0 += 32) {
        bfrag a[4], b[3];
        #pragma unroll
        for (int mi = 0; mi < 4; mi++)
            a[mi] = *(const bfrag*)(A + (size_t)ar[mi] * IN1 + k0 + lk * 8);
        #pragma unroll
        for (int ni = 0; ni < 3; ni++)
            b[ni] = *(const bfrag*)(B + (size_t)(cbase + ni * 16 + lr) * IN1 + k0 + lk * 8);
        #pragma unroll
        for (int mi = 0; mi < 4; mi++)
            #pragma unroll
            for (int ni = 0; ni < 3; ni++)
                acc[mi][ni] = __builtin_amdgcn_mfma_f32_16x16x32_bf16(a[mi], b[ni], acc[mi][ni], 0, 0, 0);
    }
    #pragma unroll
    for (int mi = 0; mi < 4; mi++) {
        #pragma unroll
        for (int ni = 0; ni < 3; ni++) {
            int col = cbase + ni * 16 + lr;
            float bia = bias[col];
            #pragma unroll
            for (int r = 0; r < 4; r++) {
                int row = rbase + mi * 16 + lk * 4 + r;
                if (row < N) proj[(size_t)row * PROJW + col] = acc[mi][ni][r] + bia;
            }
        }
    }
}

// ---------------- conv1 edge phase (flash-style online softmax) ----------------
__global__ __launch_bounds__(128) void k_conv1(
        const float* __restrict__ proj, const int* __restrict__ roff,
        const int* __restrict__ elist, float* __restrict__ h1, int N) {
    int n = blockIdx.x;
    int h = threadIdx.x >> 6;
    int lane = threadIdx.x & 63;
    size_t pb = (size_t)n * PROJW;
    float my_q = (lane < C1) ? proj[pb + h * C1 + lane] : 0.f;
    float s1v  = (lane < C1) ? proj[pb + 198 + h * C1 + lane] : 0.f;
    float m = -INFINITY, lsum = 0.f, acc = 0.f;
    int e0 = roff[n], e1 = roff[n + 1];
    const float isc = 0.17407765595569785f;  // 1/sqrt(33)
    for (int e = e0; e < e1; e++) {
        int s = elist[e];
        size_t sb = (size_t)s * PROJW;
        float kv = (lane < C1) ? proj[sb + 66 + h * C1 + lane] : 0.f;
        float vv = (lane < C1) ? proj[sb + 132 + h * C1 + lane] : 0.f;
        float prod = my_q * kv;
        #pragma unroll
        for (int off = 32; off >= 1; off >>= 1) prod += __shfl_xor(prod, off, 64);
        float alpha = prod * isc;
        float mnew = fmaxf(m, alpha);
        float scale = __expf(m - mnew);
        float p = __expf(alpha - mnew);
        lsum = lsum * scale + p;
        acc = acc * scale + p * vv;
        m = mnew;
    }
    if (lane < C1) {
        float res = (lsum > 0.f) ? acc / lsum : 0.f;
        h1[(size_t)n * D1 + h * C1 + lane] = res + s1v;
    }
}

// ---------------- precompute G = Wq2_h Wk2_h^T, bias foldings ----------------
__global__ __launch_bounds__(128) void k_precomp(
        const float* __restrict__ Wq2, const float* __restrict__ bq2,
        const float* __restrict__ Wk2, const float* __restrict__ bk2,
        float* __restrict__ G, float* __restrict__ wqbk,
        float* __restrict__ wkbq, float* __restrict__ cc) {
    int h = blockIdx.x / D1;
    int a = blockIdx.x % D1;
    const float* wqa = Wq2 + (size_t)a * D2 + h * C2;
    for (int b = threadIdx.x; b < D1; b += blockDim.x) {
        const float* wkb = Wk2 + (size_t)b * D2 + h * C2;
        float acc = 0.f;
        for (int c = 0; c < C2; c++) acc += wqa[c] * wkb[c];
        G[h * D1 * D1 + a * D1 + b] = acc;
    }
    if (threadIdx.x == 66) {
        const float* bkh = bk2 + h * C2;
        float acc = 0.f;
        for (int c = 0; c < C2; c++) acc += wqa[c] * bkh[c];
        wqbk[h * D1 + a] = acc;
    }
    if (threadIdx.x == 67) {
        const float* wka = Wk2 + (size_t)a * D2 + h * C2;
        const float* bqh = bq2 + h * C2;
        float acc = 0.f;
        for (int c = 0; c < C2; c++) acc += wka[c] * bqh[c];
        wkbq[h * D1 + a] = acc;
    }
    if (blockIdx.x == 0 && threadIdx.x >= 68 && threadIdx.x < 70) {
        int hh = threadIdx.x - 68;
        const float* bqh = bq2 + hh * C2;
        const float* bkh = bk2 + hh * C2;
        float acc = 0.f;
        for (int c = 0; c < C2; c++) acc += bqh[c] * bkh[c];
        cc[hh] = acc;
    }
}

// ---------------- z = G·h1 per node, bias dots, + U[132:224] (bf16 h1 | zeros) ----------------
__global__ __launch_bounds__(192) void k_z(
        const float* __restrict__ h1, const float* __restrict__ G,
        const float* __restrict__ wqbk, const float* __restrict__ wkbq,
        float* __restrict__ z, float* __restrict__ ad, float* __restrict__ as_,
        unsigned short* __restrict__ U, int N) {
    __shared__ float hs[D1];
    int n = blockIdx.x;
    int t = threadIdx.x;
    if (t < D1) hs[t] = h1[(size_t)n * D1 + t];
    __syncthreads();
    if (t < 2 * D1) {
        const float* Gr = G + t * D1;
        float acc = 0.f;
        for (int b = 0; b < D1; b++) acc += Gr[b] * hs[b];
        z[(size_t)n * 2 * D1 + t] = acc;
    } else if (t < 2 * D1 + 2) {
        int h = t - 2 * D1;
        const float* w = wqbk + h * D1;
        float acc = 0.f;
        for (int b = 0; b < D1; b++) acc += w[b] * hs[b];
        ad[n * 2 + h] = acc;
    } else if (t < 2 * D1 + 4) {
        int h = t - 2 * D1 - 2;
        const float* w = wkbq + h * D1;
        float acc = 0.f;
        for (int b = 0; b < D1; b++) acc += w[b] * hs[b];
        as_[n * 2 + h] = acc;
    }
    if (t < 92) U[(size_t)n * KU + 132 + t] = (t < D1) ? f2bf(hs[t]) : (unsigned short)0;
}

// ---------------- conv2 edge phase: alpha via 66-dot, aggregate h1[src] -> U bf16 ----------------
__global__ __launch_bounds__(128) void k_conv2(
        const float* __restrict__ h1, const float* __restrict__ z,
        const float* __restrict__ ad, const float* __restrict__ as_,
        const float* __restrict__ cc, const int* __restrict__ roff,
        const int* __restrict__ elist, unsigned short* __restrict__ U,
        float* __restrict__ flag, int N) {
    int n = blockIdx.x;
    int h = threadIdx.x >> 6;
    int lane = threadIdx.x & 63;
    int c0 = lane, c1 = lane + 64;
    bool ok1 = (c1 < D1);
    float hd0 = h1[(size_t)n * D1 + c0];
    float hd1 = ok1 ? h1[(size_t)n * D1 + c1] : 0.f;
    float adv = ad[n * 2 + h] + cc[h];
    float m = -INFINITY, lsum = 0.f, a0 = 0.f, a1 = 0.f;
    int e0 = roff[n], e1 = roff[n + 1];
    const float isc = 0.04264014327112209f;  // 1/sqrt(550)
    for (int e = e0; e < e1; e++) {
        int s = elist[e];
        const float* zr = z + (size_t)s * 2 * D1 + h * D1;
        float prod = hd0 * zr[c0] + (ok1 ? hd1 * zr[c1] : 0.f);
        #pragma unroll
        for (int off = 32; off >= 1; off >>= 1) prod += __shfl_xor(prod, off, 64);
        float alpha = (prod + adv + as_[s * 2 + h]) * isc;
        float mnew = fmaxf(m, alpha);
        float scale = __expf(m - mnew);
        float p = __expf(alpha - mnew);
        lsum = lsum * scale + p;
        float v0 = h1[(size_t)s * D1 + c0];
        float vv1 = ok1 ? h1[(size_t)s * D1 + c1] : 0.f;
        a0 = a0 * scale + p * v0;
        a1 = a1 * scale + p * vv1;
        m = mnew;
    }
    float inv = (lsum > 0.f) ? 1.f / lsum : 0.f;
    U[(size_t)n * KU + h * D1 + c0] = f2bf(a0 * inv);
    if (ok1) U[(size_t)n * KU + h * D1 + c1] = f2bf(a1 * inv);
    if (lane == 0) flag[n * 2 + h] = (lsum > 0.f) ? 1.f : 0.f;
}

// ---------------- MFMA GEMM 2 + epilogue: bias/flag + adjacent-pair max ----------------
__global__ __launch_bounds__(256) void k_mm2(
        const unsigned short* __restrict__ A, const unsigned short* __restrict__ B,
        const float* __restrict__ bvp, const float* __restrict__ bsp,
        const float* __restrict__ flag, float* __restrict__ out, int N) {
    int wave = threadIdx.x >> 6, lane = threadIdx.x & 63;
    int lr = lane & 15, lk = lane >> 4;
    int rbase = blockIdx.x * 128 + (wave >> 1) * 64;
    int cbase = blockIdx.y * 96 + (wave & 1) * 48;
    f32x4 acc[4][3];
    #pragma unroll
    for (int i = 0; i < 4; i++)
        #pragma unroll
        for (int j = 0; j < 3; j++) acc[i][j] = (f32x4){0.f, 0.f, 0.f, 0.f};
    int ar[4];
    #pragma unroll
    for (int mi = 0; mi < 4; mi++) {
        int r = rbase + mi * 16 + lr;
        ar[mi] = (r < N) ? r : (N - 1);
    }
    for (int k0 = 0; k0 < KU; k0 += 32) {
        bfrag a[4], b[3];
        #pragma unroll
        for (int mi = 0; mi < 4; mi++)
            a[mi] = *(const bfrag*)(A + (size_t)ar[mi] * KU + k0 + lk * 8);
        #pragma unroll
        for (int ni = 0; ni < 3; ni++)
            b[ni] = *(const bfrag*)(B + (size_t)(cbase + ni * 16 + lr) * KU + k0 + lk * 8);
        #pragma unroll
        for (int mi = 0; mi < 4; mi++)
            #pragma unroll
            for (int ni = 0; ni < 3; ni++)
                acc[mi][ni] = __builtin_amdgcn_mfma_f32_16x16x32_bf16(a[mi], b[ni], acc[mi][ni], 0, 0, 0);
    }
    #pragma unroll
    for (int mi = 0; mi < 4; mi++) {
        #pragma unroll
        for (int ni = 0; ni < 3; ni++) {
            int col = cbase + ni * 16 + lr;
            float bv = bvp[col], bs = bsp[col];
            int hh = (col >= C2) ? 1 : 0;
            #pragma unroll
            for (int r = 0; r < 4; r++) {
                int row = rbase + mi * 16 + lk * 4 + r;
                int fr = (row < N) ? row : 0;
                float val = acc[mi][ni][r] + flag[fr * 2 + hh] * bv + bs;
                float oth = __shfl_xor(val, 1, 64);
                if (row < N && col < D2 && !(col & 1))
                    out[(size_t)row * C2 + (col >> 1)] = fmaxf(val, oth);
            }
        }
    }
}

// ---------------- launcher ----------------
extern "C" void kernel_launch(void* const* d_in, const int* in_sizes, int n_in,
                              void* d_out, int out_size, void* d_ws, size_t ws_size,
                              hipStream_t stream) {
    const float* x  = (const float*)d_in[0];
    const int*   ei = (const int*)d_in[1];
    int N = in_sizes[0] / IN1;
    int E = in_sizes[1] / 2;
    const int* src = ei;
    const int* dst = ei + E;

    const float *Wq1 = (const float*)d_in[2],  *bq1 = (const float*)d_in[3];
    const float *Wk1 = (const float*)d_in[4],  *bk1 = (const float*)d_in[5];
    const float *Wv1 = (const float*)d_in[6],  *bv1 = (const float*)d_in[7];
    const float *Ws1 = (const float*)d_in[8],  *bs1 = (const float*)d_in[9];
    const float *Wq2 = (const float*)d_in[10], *bq2 = (const float*)d_in[11];
    const float *Wk2 = (const float*)d_in[12], *bk2 = (const float*)d_in[13];
    const float *Wv2 = (const float*)d_in[14], *bv2 = (const float*)d_in[15];
    const float *Ws2 = (const float*)d_in[16], *bs2 = (const float*)d_in[17];

    char* w = (char*)d_ws;
    size_t off = 0;
    auto take = [&](size_t bytes) { size_t o = off; off = (off + bytes + 255) & ~(size_t)255; return o; };

    unsigned short* xb = (unsigned short*)(w + take((size_t)N * IN1 * 2));
    size_t proj_off = take((size_t)N * PROJW * 4);
    float* proj = (float*)(w + proj_off);
    // aliased into proj region AFTER conv1 consumes proj:
    float* z = proj;                                              // N*132*4 = 10.56 MB
    unsigned short* U = (unsigned short*)(w + proj_off + (size_t)N * 132 * 4);  // N*224*2 = 8.96 MB (fits)
    float* h1   = (float*)(w + take((size_t)N * D1 * 4));
    float* ad   = (float*)(w + take((size_t)N * 2 * 4));
    float* as_  = (float*)(w + take((size_t)N * 2 * 4));
    float* flag = (float*)(w + take((size_t)N * 2 * 4));
    float* G    = (float*)(w + take((size_t)2 * D1 * D1 * 4));
    float* wqbk = (float*)(w + take(2 * D1 * 4));
    float* wkbq = (float*)(w + take(2 * D1 * 4));
    float* cc   = (float*)(w + take(2 * 4));
    unsigned short* Wt1 = (unsigned short*)(w + take((size_t)PROJW * IN1 * 2));
    float* bcat = (float*)(w + take(PROJW * 4));
    unsigned short* W2t = (unsigned short*)(w + take((size_t)N2P * KU * 2));
    float* bvp  = (float*)(w + take(N2P * 4));
    float* bsp  = (float*)(w + take(N2P * 4));
    int* cnt   = (int*)(w + take((size_t)N * 4));
    int* roff  = (int*)(w + take((size_t)(N + 1) * 4));
    int* pos   = (int*)(w + take((size_t)N * 4));
    int* elist = (int*)(w + take((size_t)E * 4));

    // CSR by dst
    hipMemsetAsync(cnt, 0, (size_t)N * sizeof(int), stream);
    k_hist<<<(E + 255) / 256, 256, 0, stream>>>(dst, E, cnt);
    k_scan<<<1, 1024, 0, stream>>>(cnt, roff, pos, N);
    k_fill<<<(E + 255) / 256, 256, 0, stream>>>(src, dst, E, pos, elist);

    // conversions + weight prep
    k_cvt<<<(N * IN1 / 4 + 255) / 256, 256, 0, stream>>>(x, xb, N * IN1 / 4);
    k_prep1<<<PROJW, 256, 0, stream>>>(Wq1, bq1, Wk1, bk1, Wv1, bv1, Ws1, bs1, Wt1, bcat);
    k_prep2<<<N2P, 256, 0, stream>>>(Wv2, bv2, Ws2, bs2, W2t, bvp, bsp);

    int mtiles = (N + 127) / 128;

    // conv1: projections (MFMA) + edge phase
    k_mm1<<<dim3(mtiles, PROJW / 96), 256, 0, stream>>>(xb, Wt1, bcat, proj, N);
    k_conv1<<<N, 128, 0, stream>>>(proj, roff, elist, h1, N);

    // conv2 precompute + z (also moves h1 -> U as bf16; safe: proj dead now)
    k_precomp<<<2 * D1, 128, 0, stream>>>(Wq2, bq2, Wk2, bk2, G, wqbk, wkbq, cc);
    k_z<<<N, 192, 0, stream>>>(h1, G, wqbk, wkbq, z, ad, as_, U, N);

    // conv2 edge phase
    k_conv2<<<N, 128, 0, stream>>>(h1, z, ad, as_, cc, roff, elist, U, flag, N);

    // final fused GEMM (MFMA) + bias + flag + pair-max
    k_mm2<<<dim3(mtiles, N2P / 96), 256, 0, stream>>>(U, W2t, bvp, bsp, flag, (float*)d_out, N);
}

// Round 3
// 257.085 us; speedup vs baseline: 2.7286x; 1.2688x over previous
//
#include <hip/hip_runtime.h>
#include <math.h>

#define HEADS 2
#define C1    33
#define C2    550
#define D1    66     // HEADS*C1
#define D2    1100   // HEADS*C2
#define IN1   256
#define PROJW 288    // padded q|k|v|s width (264 -> 288 = 3*96)
#define KU    224    // padded U width (198 -> 224 = 7*32)
#define N2P   1152   // padded final cols (1100 -> 1152 = 12*96)
#define KZ    96     // padded K for z-GEMM (66 -> 96)
#define ZW    144    // Z row stride (136 used -> 144)

typedef __attribute__((ext_vector_type(8))) short bfrag;   // 8 bf16 (bits in short)
typedef __attribute__((ext_vector_type(4))) float f32x4;

__device__ inline unsigned short f2bf(float f) {
    unsigned int u = __float_as_uint(f);
    u += 0x7FFFu + ((u >> 16) & 1u);
    return (unsigned short)(u >> 16);
}

// ---------------- fp32 -> bf16 conversion of x ----------------
__global__ void k_cvt(const float* __restrict__ x, unsigned short* __restrict__ xb, int total4) {
    int i = blockIdx.x * blockDim.x + threadIdx.x;
    if (i >= total4) return;
    float4 v = ((const float4*)x)[i];
    ushort4 o;
    o.x = f2bf(v.x); o.y = f2bf(v.y); o.z = f2bf(v.z); o.w = f2bf(v.w);
    ((ushort4*)xb)[i] = o;
}

// ---------------- build Wt1 [288][256] bf16 + bcat[288] ----------------
__global__ void k_prep1(const float* __restrict__ Wq, const float* __restrict__ bq,
                        const float* __restrict__ Wk, const float* __restrict__ bk,
                        const float* __restrict__ Wv, const float* __restrict__ bv,
                        const float* __restrict__ Ws, const float* __restrict__ bs,
                        unsigned short* __restrict__ Wt1, float* __restrict__ bcat) {
    int c = blockIdx.x;          // output col 0..287
    int k = threadIdx.x;         // 0..255
    float val = 0.f, bia = 0.f;
    if (c < 4 * D1) {
        int m = c / D1, j = c % D1;
        const float* W; const float* B;
        switch (m) {
            case 0: W = Wq; B = bq; break;
            case 1: W = Wk; B = bk; break;
            case 2: W = Wv; B = bv; break;
            default: W = Ws; B = bs; break;
        }
        val = W[(size_t)k * D1 + j];
        bia = B[j];
    }
    Wt1[(size_t)c * IN1 + k] = f2bf(val);
    if (k == 0) bcat[c] = bia;
}

// ---------------- build W2t [1152][224] bf16 + padded biases ----------------
__global__ void k_prep2(const float* __restrict__ Wv2, const float* __restrict__ bv2,
                        const float* __restrict__ Ws2, const float* __restrict__ bs2,
                        unsigned short* __restrict__ W2t,
                        float* __restrict__ bvp, float* __restrict__ bsp) {
    int c = blockIdx.x;          // 0..1151
    int k = threadIdx.x;         // 0..255 (guard 224)
    if (k < KU) {
        float val = 0.f;
        if (c < D2) {
            int h = (c >= C2) ? 1 : 0;
            if (!h) {
                if (k < 66) val = Wv2[(size_t)k * D2 + c];
                else if (k >= 132 && k < 198) val = Ws2[(size_t)(k - 132) * D2 + c];
            } else {
                if (k >= 66 && k < 132) val = Wv2[(size_t)(k - 66) * D2 + c];
                else if (k >= 132 && k < 198) val = Ws2[(size_t)(k - 132) * D2 + c];
            }
        }
        W2t[(size_t)c * KU + k] = f2bf(val);
    }
    if (k == 0) {
        bvp[c] = (c < D2) ? bv2[c] : 0.f;
        bsp[c] = (c < D2) ? bs2[c] : 0.f;
    }
}

// ---------------- CSR construction ----------------
__global__ void k_hist(const int* __restrict__ dst, int E, int* __restrict__ cnt) {
    int e = blockIdx.x * blockDim.x + threadIdx.x;
    if (e < E) atomicAdd(&cnt[dst[e]], 1);
}

__global__ void k_scan(const int* __restrict__ cnt, int* __restrict__ roff,
                       int* __restrict__ pos, int N) {
    __shared__ int wsum[16];
    __shared__ int carry_s;
    int tid = threadIdx.x, wid = tid >> 6, lane = tid & 63;
    if (tid == 0) { carry_s = 0; roff[0] = 0; }
    __syncthreads();
    for (int base = 0; base < N; base += 1024) {
        int i = base + tid;
        int v = (i < N) ? cnt[i] : 0;
        int x = v;
        #pragma unroll
        for (int s = 1; s < 64; s <<= 1) {
            int t = __shfl_up(x, s, 64);
            if (lane >= s) x += t;
        }
        if (lane == 63) wsum[wid] = x;
        __syncthreads();
        if (tid < 16) {
            int y = wsum[tid];
            #pragma unroll
            for (int s = 1; s < 16; s <<= 1) {
                int t = __shfl_up(y, s, 16);
                if (tid >= s) y += t;
            }
            wsum[tid] = y;
        }
        __syncthreads();
        int carry = carry_s;
        int incl = carry + (wid ? wsum[wid - 1] : 0) + x;
        if (i < N) { roff[i + 1] = incl; pos[i] = incl - v; }
        __syncthreads();
        if (tid == 0) carry_s = carry + wsum[15];
        __syncthreads();
    }
}

__global__ void k_fill(const int* __restrict__ src, const int* __restrict__ dst, int E,
                       int* __restrict__ pos, int* __restrict__ elist) {
    int e = blockIdx.x * blockDim.x + threadIdx.x;
    if (e < E) {
        int slot = atomicAdd(&pos[dst[e]], 1);
        elist[slot] = src[e];
    }
}

// ---------------- MFMA GEMM 1: proj[N][288] = x_bf16[N][256] @ Wt1^T + bcat ----------------
__global__ __launch_bounds__(256) void k_mm1(
        const unsigned short* __restrict__ A, const unsigned short* __restrict__ B,
        const float* __restrict__ bias, float* __restrict__ proj, int N) {
    int wave = threadIdx.x >> 6, lane = threadIdx.x & 63;
    int lr = lane & 15, lk = lane >> 4;
    int rbase = blockIdx.x * 128 + (wave >> 1) * 64;
    int cbase = blockIdx.y * 96 + (wave & 1) * 48;
    f32x4 acc[4][3];
    #pragma unroll
    for (int i = 0; i < 4; i++)
        #pragma unroll
        for (int j = 0; j < 3; j++) acc[i][j] = (f32x4){0.f, 0.f, 0.f, 0.f};
    int ar[4];
    #pragma unroll
    for (int mi = 0; mi < 4; mi++) {
        int r = rbase + mi * 16 + lr;
        ar[mi] = (r < N) ? r : (N - 1);
    }
    for (int k0 = 0; k0 < IN1; k0 += 32) {
        bfrag a[4], b[3];
        #pragma unroll
        for (int mi = 0; mi < 4; mi++)
            a[mi] = *(const bfrag*)(A + (size_t)ar[mi] * IN1 + k0 + lk * 8);
        #pragma unroll
        for (int ni = 0; ni < 3; ni++)
            b[ni] = *(const bfrag*)(B + (size_t)(cbase + ni * 16 + lr) * IN1 + k0 + lk * 8);
        #pragma unroll
        for (int mi = 0; mi < 4; mi++)
            #pragma unroll
            for (int ni = 0; ni < 3; ni++)
                acc[mi][ni] = __builtin_amdgcn_mfma_f32_16x16x32_bf16(a[mi], b[ni], acc[mi][ni], 0, 0, 0);
    }
    #pragma unroll
    for (int mi = 0; mi < 4; mi++) {
        #pragma unroll
        for (int ni = 0; ni < 3; ni++) {
            int col = cbase + ni * 16 + lr;
            float bia = bias[col];
            #pragma unroll
            for (int r = 0; r < 4; r++) {
                int row = rbase + mi * 16 + lk * 4 + r;
                if (row < N) proj[(size_t)row * PROJW + col] = acc[mi][ni][r] + bia;
            }
        }
    }
}

// ---------------- conv1 edge phase (pairwise online softmax) ----------------
__global__ __launch_bounds__(128) void k_conv1(
        const float* __restrict__ proj, const int* __restrict__ roff,
        const int* __restrict__ elist, float* __restrict__ h1,
        unsigned short* __restrict__ h1b, int N) {
    int n = blockIdx.x;
    int h = threadIdx.x >> 6;
    int lane = threadIdx.x & 63;
    size_t pb = (size_t)n * PROJW;
    bool ok = (lane < C1);
    float my_q = ok ? proj[pb + h * C1 + lane] : 0.f;
    float s1v  = ok ? proj[pb + 198 + h * C1 + lane] : 0.f;
    float m = -INFINITY, lsum = 0.f, acc = 0.f;
    int e0 = roff[n], e1 = roff[n + 1];
    const float isc = 0.17407765595569785f;  // 1/sqrt(33)
    int e = e0;
    for (; e + 1 < e1; e += 2) {
        int sa = elist[e], sb = elist[e + 1];
        size_t ba = (size_t)sa * PROJW, bb = (size_t)sb * PROJW;
        float ka = ok ? proj[ba + 66 + h * C1 + lane] : 0.f;
        float va = ok ? proj[ba + 132 + h * C1 + lane] : 0.f;
        float kb = ok ? proj[bb + 66 + h * C1 + lane] : 0.f;
        float vb = ok ? proj[bb + 132 + h * C1 + lane] : 0.f;
        float pa = my_q * ka, pbv = my_q * kb;
        #pragma unroll
        for (int off = 32; off >= 1; off >>= 1) {
            pa  += __shfl_xor(pa, off, 64);
            pbv += __shfl_xor(pbv, off, 64);
        }
        float aa = pa * isc, ab = pbv * isc;
        float mp = fmaxf(aa, ab);
        float ea = __expf(aa - mp), eb = __expf(ab - mp);
        float lp = ea + eb, ap = ea * va + eb * vb;
        float mnew = fmaxf(m, mp);
        float sc = __expf(m - mnew), sp = __expf(mp - mnew);
        lsum = lsum * sc + lp * sp;
        acc  = acc * sc + ap * sp;
        m = mnew;
    }
    if (e < e1) {
        int s = elist[e];
        size_t sb = (size_t)s * PROJW;
        float kv = ok ? proj[sb + 66 + h * C1 + lane] : 0.f;
        float vv = ok ? proj[sb + 132 + h * C1 + lane] : 0.f;
        float prod = my_q * kv;
        #pragma unroll
        for (int off = 32; off >= 1; off >>= 1) prod += __shfl_xor(prod, off, 64);
        float alpha = prod * isc;
        float mnew = fmaxf(m, alpha);
        float sc = __expf(m - mnew);
        float p = __expf(alpha - mnew);
        lsum = lsum * sc + p;
        acc  = acc * sc + p * vv;
        m = mnew;
    }
    if (ok) {
        float res = (lsum > 0.f) ? acc / lsum : 0.f;
        float val = res + s1v;
        h1[(size_t)n * D1 + h * C1 + lane] = val;
        h1b[(size_t)n * KZ + h * C1 + lane] = f2bf(val);
    } else if (h == 1 && lane >= C1 && lane < C1 + 30) {
        h1b[(size_t)n * KZ + D1 + (lane - C1)] = 0;  // zero pad cols 66..95
    }
}

// ---------------- precompute G = Wq2_h Wk2_h^T, bias foldings ----------------
__global__ __launch_bounds__(128) void k_precomp(
        const float* __restrict__ Wq2, const float* __restrict__ bq2,
        const float* __restrict__ Wk2, const float* __restrict__ bk2,
        float* __restrict__ G, float* __restrict__ wqbk,
        float* __restrict__ wkbq, float* __restrict__ cc) {
    int h = blockIdx.x / D1;
    int a = blockIdx.x % D1;
    const float* wqa = Wq2 + (size_t)a * D2 + h * C2;
    for (int b = threadIdx.x; b < D1; b += blockDim.x) {
        const float* wkb = Wk2 + (size_t)b * D2 + h * C2;
        float acc = 0.f;
        for (int c = 0; c < C2; c++) acc += wqa[c] * wkb[c];
        G[h * D1 * D1 + a * D1 + b] = acc;
    }
    if (threadIdx.x == 66) {
        const float* bkh = bk2 + h * C2;
        float acc = 0.f;
        for (int c = 0; c < C2; c++) acc += wqa[c] * bkh[c];
        wqbk[h * D1 + a] = acc;
    }
    if (threadIdx.x == 67) {
        const float* wka = Wk2 + (size_t)a * D2 + h * C2;
        const float* bqh = bq2 + h * C2;
        float acc = 0.f;
        for (int c = 0; c < C2; c++) acc += wka[c] * bqh[c];
        wkbq[h * D1 + a] = acc;
    }
    if (blockIdx.x == 0 && threadIdx.x >= 68 && threadIdx.x < 70) {
        int hh = threadIdx.x - 68;
        const float* bqh = bq2 + hh * C2;
        const float* bkh = bk2 + hh * C2;
        float acc = 0.f;
        for (int c = 0; c < C2; c++) acc += bqh[c] * bkh[c];
        cc[hh] = acc;
    }
}

// ---------------- GBt [192][96] bf16: rows 0..131 = G, 132/133 = wqbk, 134/135 = wkbq ----------------
__global__ void k_prepz(const float* __restrict__ G, const float* __restrict__ wqbk,
                        const float* __restrict__ wkbq, unsigned short* __restrict__ GBt) {
    int r = blockIdx.x;    // 0..191
    int k = threadIdx.x;   // 0..95
    float v = 0.f;
    if (k < D1) {
        if (r < 132) v = G[r * D1 + k];
        else if (r < 134) v = wqbk[(r - 132) * D1 + k];
        else if (r < 136) v = wkbq[(r - 134) * D1 + k];
    }
    GBt[r * KZ + k] = f2bf(v);
}

// ---------------- MFMA GEMM z: Z[N][144] = h1b[N][96] @ GBt^T (cols 0..135 valid) ----------------
__global__ __launch_bounds__(256) void k_mmz(
        const unsigned short* __restrict__ A, const unsigned short* __restrict__ B,
        float* __restrict__ Z, int N) {
    int wave = threadIdx.x >> 6, lane = threadIdx.x & 63;
    int lr = lane & 15, lk = lane >> 4;
    int rbase = blockIdx.x * 128 + (wave >> 1) * 64;
    int cbase = blockIdx.y * 96 + (wave & 1) * 48;
    f32x4 acc[4][3];
    #pragma unroll
    for (int i = 0; i < 4; i++)
        #pragma unroll
        for (int j = 0; j < 3; j++) acc[i][j] = (f32x4){0.f, 0.f, 0.f, 0.f};
    int ar[4];
    #pragma unroll
    for (int mi = 0; mi < 4; mi++) {
        int r = rbase + mi * 16 + lr;
        ar[mi] = (r < N) ? r : (N - 1);
    }
    for (int k0 = 0; k0 < KZ; k0 += 32) {
        bfrag a[4], b[3];
        #pragma unroll
        for (int mi = 0; mi < 4; mi++)
            a[mi] = *(const bfrag*)(A + (size_t)ar[mi] * KZ + k0 + lk * 8);
        #pragma unroll
        for (int ni = 0; ni < 3; ni++)
            b[ni] = *(const bfrag*)(B + (size_t)(cbase + ni * 16 + lr) * KZ + k0 + lk * 8);
        #pragma unroll
        for (int mi = 0; mi < 4; mi++)
            #pragma unroll
            for (int ni = 0; ni < 3; ni++)
                acc[mi][ni] = __builtin_amdgcn_mfma_f32_16x16x32_bf16(a[mi], b[ni], acc[mi][ni], 0, 0, 0);
    }
    #pragma unroll
    for (int mi = 0; mi < 4; mi++) {
        #pragma unroll
        for (int ni = 0; ni < 3; ni++) {
            int col = cbase + ni * 16 + lr;
            if (col >= 136) continue;
            #pragma unroll
            for (int r = 0; r < 4; r++) {
                int row = rbase + mi * 16 + lk * 4 + r;
                if (row < N) Z[(size_t)row * ZW + col] = acc[mi][ni][r];
            }
        }
    }
}

// ---------------- conv2 edge phase (pairwise); writes U agg + h1 bf16 copy + flag ----------------
__global__ __launch_bounds__(128) void k_conv2(
        const float* __restrict__ h1, const float* __restrict__ Z,
        const float* __restrict__ cc, const int* __restrict__ roff,
        const int* __restrict__ elist, unsigned short* __restrict__ U,
        float* __restrict__ flag, int N) {
    int n = blockIdx.x;
    int h = threadIdx.x >> 6;
    int lane = threadIdx.x & 63;
    int c0 = lane, c1 = lane + 64;
    bool ok1 = (c1 < D1);
    float hd0 = h1[(size_t)n * D1 + c0];
    float hd1 = ok1 ? h1[(size_t)n * D1 + c1] : 0.f;
    float adv = Z[(size_t)n * ZW + 132 + h] + cc[h];
    float m = -INFINITY, lsum = 0.f, a0 = 0.f, a1 = 0.f;
    int e0 = roff[n], e1 = roff[n + 1];
    const float isc = 0.04264014327112209f;  // 1/sqrt(550)
    int e = e0;
    for (; e + 1 < e1; e += 2) {
        int sa = elist[e], sb = elist[e + 1];
        const float* za = Z + (size_t)sa * ZW;
        const float* zb = Z + (size_t)sb * ZW;
        float pa = hd0 * za[h * D1 + c0] + (ok1 ? hd1 * za[h * D1 + c1] : 0.f);
        float pb = hd0 * zb[h * D1 + c0] + (ok1 ? hd1 * zb[h * D1 + c1] : 0.f);
        #pragma unroll
        for (int off = 32; off >= 1; off >>= 1) {
            pa += __shfl_xor(pa, off, 64);
            pb += __shfl_xor(pb, off, 64);
        }
        float aa = (pa + adv + za[134 + h]) * isc;
        float ab = (pb + adv + zb[134 + h]) * isc;
        float va0 = h1[(size_t)sa * D1 + c0];
        float va1 = ok1 ? h1[(size_t)sa * D1 + c1] : 0.f;
        float vb0 = h1[(size_t)sb * D1 + c0];
        float vb1 = ok1 ? h1[(size_t)sb * D1 + c1] : 0.f;
        float mp = fmaxf(aa, ab);
        float ea = __expf(aa - mp), eb = __expf(ab - mp);
        float lp = ea + eb;
        float ap0 = ea * va0 + eb * vb0;
        float ap1 = ea * va1 + eb * vb1;
        float mnew = fmaxf(m, mp);
        float sc = __expf(m - mnew), sp = __expf(mp - mnew);
        lsum = lsum * sc + lp * sp;
        a0 = a0 * sc + ap0 * sp;
        a1 = a1 * sc + ap1 * sp;
        m = mnew;
    }
    if (e < e1) {
        int s = elist[e];
        const float* zr = Z + (size_t)s * ZW;
        float prod = hd0 * zr[h * D1 + c0] + (ok1 ? hd1 * zr[h * D1 + c1] : 0.f);
        #pragma unroll
        for (int off = 32; off >= 1; off >>= 1) prod += __shfl_xor(prod, off, 64);
        float alpha = (prod + adv + zr[134 + h]) * isc;
        float mnew = fmaxf(m, alpha);
        float sc = __expf(m - mnew);
        float p = __expf(alpha - mnew);
        lsum = lsum * sc + p;
        float v0 = h1[(size_t)s * D1 + c0];
        float vv1 = ok1 ? h1[(size_t)s * D1 + c1] : 0.f;
        a0 = a0 * sc + p * v0;
        a1 = a1 * sc + p * vv1;
        m = mnew;
    }
    float inv = (lsum > 0.f) ? 1.f / lsum : 0.f;
    size_t ub = (size_t)n * KU;
    U[ub + h * D1 + c0] = f2bf(a0 * inv);
    if (ok1) U[ub + h * D1 + c1] = f2bf(a1 * inv);
    // h1 bf16 copy into U[132..197]; zero pad U[198..223]
    if (h == 0) {
        U[ub + 132 + c0] = f2bf(hd0);
        if (ok1) U[ub + 132 + c1] = f2bf(hd1);
    } else if (lane < KU - 198) {
        U[ub + 198 + lane] = 0;
    }
    if (lane == 0) flag[n * 2 + h] = (lsum > 0.f) ? 1.f : 0.f;
}

// ---------------- MFMA GEMM 2 + epilogue: bias/flag + adjacent-pair max ----------------
__global__ __launch_bounds__(256) void k_mm2(
        const unsigned short* __restrict__ A, const unsigned short* __restrict__ B,
        const float* __restrict__ bvp, const float* __restrict__ bsp,
        const float* __restrict__ flag, float* __restrict__ out, int N) {
    int wave = threadIdx.x >> 6, lane = threadIdx.x & 63;
    int lr = lane & 15, lk = lane >> 4;
    int rbase = blockIdx.x * 128 + (wave >> 1) * 64;
    int cbase = blockIdx.y * 96 + (wave & 1) * 48;
    f32x4 acc[4][3];
    #pragma unroll
    for (int i = 0; i < 4; i++)
        #pragma unroll
        for (int j = 0; j < 3; j++) acc[i][j] = (f32x4){0.f, 0.f, 0.f, 0.f};
    int ar[4];
    #pragma unroll
    for (int mi = 0; mi < 4; mi++) {
        int r = rbase + mi * 16 + lr;
        ar[mi] = (r < N) ? r : (N - 1);
    }
    for (int k0 = 0; k0 < KU; k0 += 32) {
        bfrag a[4], b[3];
        #pragma unroll
        for (int mi = 0; mi < 4; mi++)
            a[mi] = *(const bfrag*)(A + (size_t)ar[mi] * KU + k0 + lk * 8);
        #pragma unroll
        for (int ni = 0; ni < 3; ni++)
            b[ni] = *(const bfrag*)(B + (size_t)(cbase + ni * 16 + lr) * KU + k0 + lk * 8);
        #pragma unroll
        for (int mi = 0; mi < 4; mi++)
            #pragma unroll
            for (int ni = 0; ni < 3; ni++)
                acc[mi][ni] = __builtin_amdgcn_mfma_f32_16x16x32_bf16(a[mi], b[ni], acc[mi][ni], 0, 0, 0);
    }
    #pragma unroll
    for (int mi = 0; mi < 4; mi++) {
        #pragma unroll
        for (int ni = 0; ni < 3; ni++) {
            int col = cbase + ni * 16 + lr;
            float bv = bvp[col], bs = bsp[col];
            int hh = (col >= C2) ? 1 : 0;
            #pragma unroll
            for (int r = 0; r < 4; r++) {
                int row = rbase + mi * 16 + lk * 4 + r;
                int fr = (row < N) ? row : 0;
                float val = acc[mi][ni][r] + flag[fr * 2 + hh] * bv + bs;
                float oth = __shfl_xor(val, 1, 64);
                if (row < N && col < D2 && !(col & 1))
                    out[(size_t)row * C2 + (col >> 1)] = fmaxf(val, oth);
            }
        }
    }
}

// ---------------- launcher ----------------
extern "C" void kernel_launch(void* const* d_in, const int* in_sizes, int n_in,
                              void* d_out, int out_size, void* d_ws, size_t ws_size,
                              hipStream_t stream) {
    const float* x  = (const float*)d_in[0];
    const int*   ei = (const int*)d_in[1];
    int N = in_sizes[0] / IN1;
    int E = in_sizes[1] / 2;
    const int* src = ei;
    const int* dst = ei + E;

    const float *Wq1 = (const float*)d_in[2],  *bq1 = (const float*)d_in[3];
    const float *Wk1 = (const float*)d_in[4],  *bk1 = (const float*)d_in[5];
    const float *Wv1 = (const float*)d_in[6],  *bv1 = (const float*)d_in[7];
    const float *Ws1 = (const float*)d_in[8],  *bs1 = (const float*)d_in[9];
    const float *Wq2 = (const float*)d_in[10], *bq2 = (const float*)d_in[11];
    const float *Wk2 = (const float*)d_in[12], *bk2 = (const float*)d_in[13];
    const float *Wv2 = (const float*)d_in[14], *bv2 = (const float*)d_in[15];
    const float *Ws2 = (const float*)d_in[16], *bs2 = (const float*)d_in[17];

    char* w = (char*)d_ws;
    size_t off = 0;
    auto take = [&](size_t bytes) { size_t o = off; off = (off + bytes + 255) & ~(size_t)255; return o; };

    unsigned short* xb = (unsigned short*)(w + take((size_t)N * IN1 * 2));
    size_t proj_off = take((size_t)N * PROJW * 4);
    float* proj = (float*)(w + proj_off);
    // aliased into proj region AFTER conv1 consumes proj:
    float* Z = proj;                                                       // N*144*4 = 11.52 MB
    unsigned short* U = (unsigned short*)(w + proj_off + (size_t)N * ZW * 4);  // N*224*2 = 8.96 MB
    float* h1   = (float*)(w + take((size_t)N * D1 * 4));
    unsigned short* h1b = (unsigned short*)(w + take((size_t)N * KZ * 2));
    float* flag = (float*)(w + take((size_t)N * 2 * 4));
    float* G    = (float*)(w + take((size_t)2 * D1 * D1 * 4));
    float* wqbk = (float*)(w + take(2 * D1 * 4));
    float* wkbq = (float*)(w + take(2 * D1 * 4));
    float* cc   = (float*)(w + take(2 * 4));
    unsigned short* GBt = (unsigned short*)(w + take((size_t)192 * KZ * 2));
    unsigned short* Wt1 = (unsigned short*)(w + take((size_t)PROJW * IN1 * 2));
    float* bcat = (float*)(w + take(PROJW * 4));
    unsigned short* W2t = (unsigned short*)(w + take((size_t)N2P * KU * 2));
    float* bvp  = (float*)(w + take(N2P * 4));
    float* bsp  = (float*)(w + take(N2P * 4));
    int* cnt   = (int*)(w + take((size_t)N * 4));
    int* roff  = (int*)(w + take((size_t)(N + 1) * 4));
    int* pos   = (int*)(w + take((size_t)N * 4));
    int* elist = (int*)(w + take((size_t)E * 4));

    // CSR by dst
    hipMemsetAsync(cnt, 0, (size_t)N * sizeof(int), stream);
    k_hist<<<(E + 255) / 256, 256, 0, stream>>>(dst, E, cnt);
    k_scan<<<1, 1024, 0, stream>>>(cnt, roff, pos, N);
    k_fill<<<(E + 255) / 256, 256, 0, stream>>>(src, dst, E, pos, elist);

    // conversions + weight prep
    k_cvt<<<(N * IN1 / 4 + 255) / 256, 256, 0, stream>>>(x, xb, N * IN1 / 4);
    k_prep1<<<PROJW, 256, 0, stream>>>(Wq1, bq1, Wk1, bk1, Wv1, bv1, Ws1, bs1, Wt1, bcat);
    k_prep2<<<N2P, 256, 0, stream>>>(Wv2, bv2, Ws2, bs2, W2t, bvp, bsp);
    k_precomp<<<2 * D1, 128, 0, stream>>>(Wq2, bq2, Wk2, bk2, G, wqbk, wkbq, cc);
    k_prepz<<<192, KZ, 0, stream>>>(G, wqbk, wkbq, GBt);

    int mtiles = (N + 127) / 128;

    // conv1: projections (MFMA) + edge phase
    k_mm1<<<dim3(mtiles, PROJW / 96), 256, 0, stream>>>(xb, Wt1, bcat, proj, N);
    k_conv1<<<N, 128, 0, stream>>>(proj, roff, elist, h1, h1b, N);

    // z-GEMM (MFMA): Z = h1b @ GBt^T  (also yields ad/as columns 132..135)
    k_mmz<<<dim3(mtiles, 2), 256, 0, stream>>>(h1b, GBt, Z, N);

    // conv2 edge phase (writes U: agg bf16 + h1 bf16 + pad)
    k_conv2<<<N, 128, 0, stream>>>(h1, Z, cc, roff, elist, U, flag, N);

    // final fused GEMM (MFMA) + bias + flag + pair-max
    k_mm2<<<dim3(mtiles, N2P / 96), 256, 0, stream>>>(U, W2t, bvp, bsp, flag, (float*)d_out, N);
}